// Round 13
// baseline (170.521 us; speedup 1.0000x reference)
//
#include <hip/hip_runtime.h>
#include <stdint.h>

#define NQ 8192
#define BSZ 8
#define NH 8
#define NP 4
#define HD 32
#define EMBED 256
#define IMG 128          // H == W == 128
#define NPIX (IMG*IMG)

typedef __attribute__((ext_vector_type(8))) short short8v;   // 8 bf16 (4 VGPR)
typedef __attribute__((ext_vector_type(4))) float f32x4;

static __device__ __forceinline__ float bf2f(uint32_t u) {
    union { uint32_t i; float f; } x; x.i = u << 16; return x.f;
}
static __device__ __forceinline__ uint16_t f2bf(float f) {
    union { float f; uint32_t i; } x; x.f = f;
    uint32_t r = x.i + 0x7fffu + ((x.i >> 16) & 1u);   // RNE
    return (uint16_t)(r >> 16);
}
static __device__ __forceinline__ uint32_t cvtpk(float lo, float hi) {
    uint32_t r;
    asm("v_cvt_pk_bf16_f32 %0, %1, %2" : "=v"(r) : "v"(lo), "v"(hi));
    return r;
}
static __device__ __forceinline__ void gload_lds16(const void* g, void* l) {
    __builtin_amdgcn_global_load_lds(
        (const __attribute__((address_space(1))) unsigned int*)g,
        (__attribute__((address_space(3))) unsigned int*)l, 16, 0, 0);
}

// ---------------------------------------------------------------------------
// pack: build transposed bf16 weights.  wT[n][k] = w[k][n]
// ---------------------------------------------------------------------------
__global__ void pack_w(const float* __restrict__ w_val, const float* __restrict__ w_out,
                       const float* __restrict__ w_off, const float* __restrict__ w_attn,
                       uint16_t* __restrict__ wTval, uint16_t* __restrict__ wTout,
                       uint16_t* __restrict__ wTcat) {
    int k = blockIdx.x;          // 0..255
    int n = threadIdx.x;         // 0..255
    wTval[n * 256 + k] = f2bf(w_val[k * 256 + n]);
    wTout[n * 256 + k] = f2bf(w_out[k * 256 + n]);
    if (n < 64)       wTcat[n * 256 + k]        = f2bf(w_off[k * 64 + n]);
    else if (n < 96)  wTcat[n * 256 + k]        = f2bf(w_attn[k * 32 + (n - 64)]);
}

// ---------------------------------------------------------------------------
// cvt: value f32 -> bf16 in MFMA-FRAGMENT-TILE order:
//   out chunk gid (16B) = [tile][k][lane]: tile=gid>>9, k=(gid>>6)&7, l=gid&63
//   content = A row (tile*16 + (l&15)), cols k*32 + (l>>4)*8 .. +8.
// Writes perfectly linear; reads 2xfloat4 per thread (L1-absorbed windows).
// ---------------------------------------------------------------------------
__global__ __launch_bounds__(256)
void cvt_kernel(const float* __restrict__ in, uint16_t* __restrict__ out) {
    const int stride = gridDim.x * 256;
    for (int gid = blockIdx.x * 256 + threadIdx.x; gid < 4194304; gid += stride) {
        int tile = gid >> 9;
        int k = (gid >> 6) & 7;
        int l = gid & 63;
        const float* src = in + ((size_t)tile * 16 + (l & 15)) * 256 + k * 32 + (l >> 4) * 8;
        float4 f0 = ((const float4*)src)[0];
        float4 f1 = ((const float4*)src)[1];
        uint4 o;
        o.x = cvtpk(f0.x, f0.y); o.y = cvtpk(f0.z, f0.w);
        o.z = cvtpk(f1.x, f1.y); o.w = cvtpk(f1.z, f1.w);
        ((uint4*)out)[gid] = o;
    }
}

// ---------------------------------------------------------------------------
// vproj waveGEMM: NO barriers, NO shared staging. 512 blocks x 256 thr
// (4 waves, 2 blocks/CU). Block owns 16 tiles (256 rows). Wave w owns
// cols w*64..+64 (heads 2w,2w+1), breg[4][8] from global (L2-hot).
// A fragments load global->reg as 8 x 1KB fully-linear wave-loads per tile
// (fragment-tile-ordered abf16). Register double-buffer aA/aB (static).
// v-store via wave-PRIVATE 2KB LDS transpose (lgkmcnt only) -> 2 x 1KB
// contiguous dwordx4 store-instrs per tile.
// ---------------------------------------------------------------------------
__global__ __launch_bounds__(256, 2)
void vproj_gemm(const uint16_t* __restrict__ Af, const uint16_t* __restrict__ BT,
                uint16_t* __restrict__ Vp, const float* __restrict__ bias) {
    __shared__ char LDSW[4][2048];
    const int tid = threadIdx.x, w = tid >> 6, l = tid & 63;
    const int r16 = l & 15, kq = l >> 4;
    const int bid = blockIdx.x;
    char* ldw = LDSW[w];
    const char* abase = (const char*)Af + (size_t)bid * 16 * 8192;

    short8v breg[4][8];
    float bv[4];
#pragma unroll
    for (int n = 0; n < 4; ++n) {
        const int col = w * 64 + n * 16 + r16;
        bv[n] = bias[col];
        const char* bb = (const char*)BT + (size_t)col * 512 + kq * 16;
#pragma unroll
        for (int k = 0; k < 8; ++k)
            breg[n][k] = *(const short8v*)(bb + k * 64);
    }

    short8v aA[8], aB[8];
    auto LOAD = [&](short8v (&a)[8], int t) {
        const char* p = abase + (size_t)t * 8192 + l * 16;
#pragma unroll
        for (int k = 0; k < 8; ++k)
            a[k] = *(const short8v*)(p + k * 1024);
    };
    auto CSTORE = [&](const short8v (&a)[8], int t) {
        f32x4 acc[4] = {};
#pragma unroll
        for (int k = 0; k < 8; ++k)
#pragma unroll
            for (int n = 0; n < 4; ++n)
                acc[n] = __builtin_amdgcn_mfma_f32_16x16x32_bf16(a[k], breg[n][k], acc[n], 0, 0, 0);
        // transpose via wave-private LDS: [2 heads][16 pix][64B]
#pragma unroll
        for (int n = 0; n < 4; ++n) {
            const int hh = n >> 1, d = (n & 1) * 16 + r16;
#pragma unroll
            for (int r = 0; r < 4; ++r)
                *(uint16_t*)(ldw + hh * 1024 + (kq * 4 + r) * 64 + d * 2)
                    = f2bf(acc[n][r] + bv[n]);
        }
        const int gr0 = bid * 256 + t * 16;
        const int b_ = gr0 >> 14, pix0 = gr0 & 16383;
#pragma unroll
        for (int hh = 0; hh < 2; ++hh) {
            const int h = w * 2 + hh;
            uint4 d = *(const uint4*)(ldw + hh * 1024 + l * 16);
            *(uint4*)((char*)Vp + (((size_t)(b_ * 8 + h)) << 20)
                      + (size_t)pix0 * 64 + l * 16) = d;
        }
    };

    LOAD(aA, 0);
#pragma unroll
    for (int tt = 0; tt < 8; ++tt) {
        const int t0 = tt * 2, t1 = t0 + 1;
        LOAD(aB, t1);
        CSTORE(aA, t0);
        if (t0 + 2 < 16) LOAD(aA, t0 + 2);
        CSTORE(aB, t1);
    }
}

// ---------------------------------------------------------------------------
// oproj waveGEMM: same scheme. 512 blocks x 256 thr, block owns 8 tiles
// (128 rows). A = oatt in fragment-tile order (written by sample_kernel).
// C row-major f32 via wave-private 4KB LDS transpose -> 4 x 1KB stores/tile.
// ---------------------------------------------------------------------------
__global__ __launch_bounds__(256, 2)
void oproj_gemm(const uint16_t* __restrict__ Af, const uint16_t* __restrict__ BT,
                float* __restrict__ C, const float* __restrict__ bias) {
    __shared__ char LDSW[4][4096];
    const int tid = threadIdx.x, w = tid >> 6, l = tid & 63;
    const int r16 = l & 15, kq = l >> 4;
    const int bid = blockIdx.x;
    char* ldw = LDSW[w];
    const char* abase = (const char*)Af + (size_t)bid * 8 * 8192;

    short8v breg[4][8];
    float bv[4];
#pragma unroll
    for (int n = 0; n < 4; ++n) {
        const int col = w * 64 + n * 16 + r16;
        bv[n] = bias[col];
        const char* bb = (const char*)BT + (size_t)col * 512 + kq * 16;
#pragma unroll
        for (int k = 0; k < 8; ++k)
            breg[n][k] = *(const short8v*)(bb + k * 64);
    }

    short8v aA[8], aB[8];
    auto LOAD = [&](short8v (&a)[8], int t) {
        const char* p = abase + (size_t)t * 8192 + l * 16;
#pragma unroll
        for (int k = 0; k < 8; ++k)
            a[k] = *(const short8v*)(p + k * 1024);
    };
    auto CSTORE = [&](const short8v (&a)[8], int t) {
        f32x4 acc[4] = {};
#pragma unroll
        for (int k = 0; k < 8; ++k)
#pragma unroll
            for (int n = 0; n < 4; ++n)
                acc[n] = __builtin_amdgcn_mfma_f32_16x16x32_bf16(a[k], breg[n][k], acc[n], 0, 0, 0);
        // wave-private LDS [16 rows][64 f32]
#pragma unroll
        for (int n = 0; n < 4; ++n)
#pragma unroll
            for (int r = 0; r < 4; ++r)
                *(float*)(ldw + (kq * 4 + r) * 256 + (n * 16 + r16) * 4)
                    = acc[n][r] + bv[n];
        const int gr0 = bid * 128 + t * 16;
#pragma unroll
        for (int i = 0; i < 4; ++i) {
            const int fb = i * 1024 + l * 16;
            const int row = fb >> 8, cb = fb & 255;
            uint4 d = *(const uint4*)(ldw + fb);
            *(uint4*)((char*)C + (size_t)(gr0 + row) * 1024 + w * 256 + cb) = d;
        }
    };

    LOAD(aA, 0);
#pragma unroll
    for (int tt = 0; tt < 4; ++tt) {
        const int t0 = tt * 2, t1 = t0 + 1;
        LOAD(aB, t1);
        CSTORE(aA, t0);
        if (t0 + 2 < 8) LOAD(aA, t0 + 2);
        CSTORE(aB, t1);
    }
}

// ---------------------------------------------------------------------------
// proj: per 64 query rows, GEMM query[64x256] @ wTcat^T -> scores[64x96],
// then per (row, head): softmax + sampling locations, written HEAD-MAJOR:
//   itemH = ((b*8+h)*8192 + q);  locs[itemH][8], attnw[itemH][4]
// ---------------------------------------------------------------------------
__global__ __launch_bounds__(256, 2)
void proj_kernel(const float* __restrict__ Q, const uint16_t* __restrict__ WTcat,
                 const float* __restrict__ b_off, const float* __restrict__ b_attn,
                 const float* __restrict__ refp,
                 float* __restrict__ locs, float* __restrict__ attnw) {
    __shared__ uint16_t Bs[96 * 256];   // 48KB, [col][k], swizzled (512B rows)
    __shared__ uint16_t As[64 * 256];   // 32KB, [row][k], swizzled; reused as scores
    const int tid = threadIdx.x, w = tid >> 6, l = tid & 63;
    const int blk = blockIdx.x;

#pragma unroll
    for (int c = 0; c < 12; ++c) {
        int loff = (w * 12 + c) * 1024;
        int lofl = loff + l * 16;
        int row = lofl >> 9, colb = lofl & 511;
        const char* src = (const char*)WTcat + (size_t)row * 512 + (colb ^ ((row & 7) << 4));
        gload_lds16(src, (char*)Bs + loff);
    }
#pragma unroll
    for (int c = 0; c < 8; ++c) {
        int loff = tid * 16 + c * 4096;
        int row = loff >> 9, colb = loff & 511;
        const float* src = Q + (size_t)(blk * 64 + row) * 256 + (colb >> 1);
        float4 f0 = *(const float4*)src;
        float4 f1 = *(const float4*)(src + 4);
        uint4 pk;
        pk.x = (uint32_t)f2bf(f0.x) | ((uint32_t)f2bf(f0.y) << 16);
        pk.y = (uint32_t)f2bf(f0.z) | ((uint32_t)f2bf(f0.w) << 16);
        pk.z = (uint32_t)f2bf(f1.x) | ((uint32_t)f2bf(f1.y) << 16);
        pk.w = (uint32_t)f2bf(f1.z) | ((uint32_t)f2bf(f1.w) << 16);
        *(uint4*)((char*)As + row * 512 + (colb ^ ((row & 7) << 4))) = pk;
    }
    __syncthreads();

    f32x4 acc[6] = {};
    const int arow = w * 16 + (l & 15);
#pragma unroll
    for (int ks = 0; ks < 8; ++ks) {
        const int kb = ks * 64 + (l >> 4) * 16;
        short8v a = *(const short8v*)((const char*)As + arow * 512 + (kb ^ ((arow & 7) << 4)));
#pragma unroll
        for (int n = 0; n < 6; ++n) {
            int col = n * 16 + (l & 15);
            short8v b = *(const short8v*)((const char*)Bs + col * 512 + (kb ^ ((col & 7) << 4)));
            acc[n] = __builtin_amdgcn_mfma_f32_16x16x32_bf16(a, b, acc[n], 0, 0, 0);
        }
    }
    __syncthreads();
    float* scores = (float*)As;   // [64][96]
#pragma unroll
    for (int n = 0; n < 6; ++n)
#pragma unroll
        for (int r = 0; r < 4; ++r)
            scores[(w * 16 + (l >> 4) * 4 + r) * 96 + n * 16 + (l & 15)] = acc[n][r];
    __syncthreads();

    for (int it = tid; it < 512; it += 256) {
        int row = it >> 3, h = it & 7;
        int gq = blk * 64 + row;                       // b*NQ + q
        int b = gq >> 13, q = gq & 8191;
        size_t itemH = ((size_t)(b * 8 + h) << 13) | q;
        float s0 = scores[row * 96 + 64 + h * 4 + 0] + b_attn[h * 4 + 0];
        float s1 = scores[row * 96 + 64 + h * 4 + 1] + b_attn[h * 4 + 1];
        float s2 = scores[row * 96 + 64 + h * 4 + 2] + b_attn[h * 4 + 2];
        float s3 = scores[row * 96 + 64 + h * 4 + 3] + b_attn[h * 4 + 3];
        float mx = fmaxf(fmaxf(s0, s1), fmaxf(s2, s3));
        float e0 = __expf(s0 - mx), e1 = __expf(s1 - mx);
        float e2 = __expf(s2 - mx), e3 = __expf(s3 - mx);
        float inv = 1.0f / (e0 + e1 + e2 + e3);
        float rx = refp[gq * 2 + 0] * 128.0f - 0.5f;
        float ry = refp[gq * 2 + 1] * 128.0f - 0.5f;
        float ew[4] = { e0, e1, e2, e3 };
#pragma unroll
        for (int p = 0; p < 4; ++p) {
            float ox = scores[row * 96 + h * 8 + p * 2 + 0] + b_off[h * 8 + p * 2 + 0];
            float oy = scores[row * 96 + h * 8 + p * 2 + 1] + b_off[h * 8 + p * 2 + 1];
            locs[itemH * 8 + p * 2 + 0] = rx + ox;
            locs[itemH * 8 + p * 2 + 1] = ry + oy;
            attnw[itemH * 4 + p] = ew[p] * inv;
        }
    }
}

// ---------------------------------------------------------------------------
// sample: plane-major v[b][h][16384][32] bf16 (1MB per (b,h) plane).
// XCD-pinned: blockIdx&7 = h; 4 lanes/item, dwordx4 gathers.
// oatt written in FRAGMENT-TILE order: byte = tile*8192 + h*1024 +
// ((dg*16 + (bq&15))*16)  [k=h, kq=dg, row=bq&15] — per wave this exactly
// tiles a 1KB block.
// ---------------------------------------------------------------------------
__global__ __launch_bounds__(256)
void sample_kernel(const uint16_t* __restrict__ v, const float* __restrict__ locs,
                   const float* __restrict__ attnw, uint16_t* __restrict__ oatt) {
    const int bid = blockIdx.x;          // 8192 blocks
    const int h = bid & 7;
    const int rest = bid >> 3;           // 0..1023
    const int b = rest >> 7;             // 0..7
    const int chunk = rest & 127;        // 0..127
    const int qloc = threadIdx.x >> 2;   // 0..63
    const int dg = threadIdx.x & 3;      // dims dg*8..dg*8+7
    const int q = chunk * 64 + qloc;
    const size_t itemH = ((size_t)(b * 8 + h) << 13) | q;
    const char* plane = (const char*)v + ((size_t)(b * 8 + h) << 20);   // 1MB planes

    float4 l01 = ((const float4*)locs)[itemH * 2 + 0];
    float4 l23 = ((const float4*)locs)[itemH * 2 + 1];
    float4 aw4 = ((const float4*)attnw)[itemH];
    float pxs[4] = { l01.x, l01.z, l23.x, l23.z };
    float pys[4] = { l01.y, l01.w, l23.y, l23.w };
    float aws[4] = { aw4.x, aw4.y, aw4.z, aw4.w };

    float acc[8] = {};
#pragma unroll
    for (int p = 0; p < 4; ++p) {
        float px = pxs[p], py = pys[p], aw = aws[p];
        float fx = floorf(px), fy = floorf(py);
        float wx = px - fx, wy = py - fy;
        int x0 = (int)fx, y0 = (int)fy;
#pragma unroll
        for (int cy = 0; cy < 2; ++cy) {
            int yy = y0 + cy;
            float wyv = cy ? wy : 1.f - wy;
            bool yok = (unsigned)yy < (unsigned)IMG;
            int yc = min(max(yy, 0), IMG - 1);
#pragma unroll
            for (int cx = 0; cx < 2; ++cx) {
                int xx = x0 + cx;
                bool ok = yok && ((unsigned)xx < (unsigned)IMG);
                int xc = min(max(xx, 0), IMG - 1);
                float wgt = ok ? aw * (cx ? wx : 1.f - wx) * wyv : 0.f;
                const uint4 u = *(const uint4*)(plane + ((size_t)(yc * IMG + xc) << 6) + dg * 16);
                acc[0] += wgt * bf2f(u.x & 0xffffu);
                acc[1] += wgt * bf2f(u.x >> 16);
                acc[2] += wgt * bf2f(u.y & 0xffffu);
                acc[3] += wgt * bf2f(u.y >> 16);
                acc[4] += wgt * bf2f(u.z & 0xffffu);
                acc[5] += wgt * bf2f(u.z >> 16);
                acc[6] += wgt * bf2f(u.w & 0xffffu);
                acc[7] += wgt * bf2f(u.w >> 16);
            }
        }
    }
    const size_t bq = (size_t)b * NQ + q;
    uint4 out;
    out.x = (uint32_t)f2bf(acc[0]) | ((uint32_t)f2bf(acc[1]) << 16);
    out.y = (uint32_t)f2bf(acc[2]) | ((uint32_t)f2bf(acc[3]) << 16);
    out.z = (uint32_t)f2bf(acc[4]) | ((uint32_t)f2bf(acc[5]) << 16);
    out.w = (uint32_t)f2bf(acc[6]) | ((uint32_t)f2bf(acc[7]) << 16);
    const size_t tile = bq >> 4;
    const int row = (int)(bq & 15);
    *(uint4*)((char*)oatt + tile * 8192 + h * 1024 + (size_t)(dg * 16 + row) * 16) = out;
}

// ---------------------------------------------------------------------------
extern "C" void kernel_launch(void* const* d_in, const int* in_sizes, int n_in,
                              void* d_out, int out_size, void* d_ws, size_t ws_size,
                              hipStream_t stream) {
    const float* query  = (const float*)d_in[0];
    const float* refp   = (const float*)d_in[1];
    const float* value  = (const float*)d_in[2];
    const float* w_off  = (const float*)d_in[3];
    const float* b_off  = (const float*)d_in[4];
    const float* w_attn = (const float*)d_in[5];
    const float* b_attn = (const float*)d_in[6];
    const float* w_val  = (const float*)d_in[7];
    const float* b_val  = (const float*)d_in[8];
    const float* w_out  = (const float*)d_in[9];
    const float* b_out  = (const float*)d_in[10];

    char* ws = (char*)d_ws;
    uint16_t* v     = (uint16_t*)(ws);                    //  64 MB  [b][h][pix][32]
    uint16_t* oatt  = (uint16_t*)(ws + (64u << 20));      //  32 MB  fragment-tile order
    float*    locs  = (float*)(ws + (96u << 20));         //  16 MB  head-major
    float*    attnw = (float*)(ws + (112u << 20));        //   8 MB  head-major
    uint16_t* wTval = (uint16_t*)(ws + (120u << 20));     // 128 KB
    uint16_t* wTout = (uint16_t*)(ws + (120u << 20) + 131072);
    uint16_t* wTcat = (uint16_t*)(ws + (120u << 20) + 262144);
    uint16_t* abf16 = (uint16_t*)(ws + (192u << 20));     //  64 MB  value, fragment-tile order

    pack_w<<<256, 256, 0, stream>>>(w_val, w_out, w_off, w_attn, wTval, wTout, wTcat);
    // value f32 -> bf16 fragment-tile order (streaming)
    cvt_kernel<<<4096, 256, 0, stream>>>(value, abf16);
    // value projection: barrier-free wave-GEMM -> v (plane-major bf16)
    vproj_gemm<<<512, 256, 0, stream>>>(abf16, wTval, v, b_val);
    // query projections + softmax + locations (head-major records)
    proj_kernel<<<1024, 256, 0, stream>>>(query, wTcat, b_off, b_attn, refp, locs, attnw);
    // bilinear sampling -> oatt (fragment-tile order bf16)
    sample_kernel<<<8192, 256, 0, stream>>>(v, locs, attnw, oatt);
    // output projection: barrier-free wave-GEMM -> f32 d_out
    oproj_gemm<<<512, 256, 0, stream>>>(oatt, wTout, (float*)d_out, b_out);
}

// Round 14
// 138.561 us; speedup vs baseline: 1.2307x; 1.2307x over previous
//
#include <hip/hip_runtime.h>
#include <stdint.h>

#define NQ 8192
#define BSZ 8
#define NH 8
#define NP 4
#define HD 32
#define EMBED 256
#define IMG 128          // H == W == 128
#define NPIX (IMG*IMG)

typedef __attribute__((ext_vector_type(8))) short short8v;   // 8 bf16 (4 VGPR)
typedef __attribute__((ext_vector_type(4))) float f32x4;

static __device__ __forceinline__ float bf2f(uint32_t u) {
    union { uint32_t i; float f; } x; x.i = u << 16; return x.f;
}
static __device__ __forceinline__ uint16_t f2bf(float f) {
    union { float f; uint32_t i; } x; x.f = f;
    uint32_t r = x.i + 0x7fffu + ((x.i >> 16) & 1u);   // RNE
    return (uint16_t)(r >> 16);
}
static __device__ __forceinline__ uint32_t cvtpk(float lo, float hi) {
    uint32_t r;
    asm("v_cvt_pk_bf16_f32 %0, %1, %2" : "=v"(r) : "v"(lo), "v"(hi));
    return r;
}
static __device__ __forceinline__ void gload_lds16(const void* g, void* l) {
    __builtin_amdgcn_global_load_lds(
        (const __attribute__((address_space(1))) unsigned int*)g,
        (__attribute__((address_space(3))) unsigned int*)l, 16, 0, 0);
}

// NO sched_barrier(0) anywhere: m141 measured the order-pin at ~1.7x cost.
// Memory-clobber asm is the only compiler fence; s_barrier is the wave fence.
#define WAITV(n)   asm volatile("s_waitcnt vmcnt(" #n ")" ::: "memory")
#define WAITLGKM() asm volatile("s_waitcnt lgkmcnt(0)" ::: "memory")
#define BAR()      __builtin_amdgcn_s_barrier()
#define CLOBBER()  asm volatile("" ::: "memory")

static __device__ __forceinline__ void waitv_n(int n) {
    switch (n) {
        case 0: WAITV(0); break;  case 1: WAITV(1); break;
        case 2: WAITV(2); break;  case 3: WAITV(3); break;
        case 4: WAITV(4); break;  case 5: WAITV(5); break;
        case 6: WAITV(6); break;  case 8: WAITV(8); break;
        default: WAITV(10); break;
    }
}

// ---------------------------------------------------------------------------
// pack: build transposed bf16 weights.  wT[n][k] = w[k][n]
// ---------------------------------------------------------------------------
__global__ void pack_w(const float* __restrict__ w_val, const float* __restrict__ w_out,
                       const float* __restrict__ w_off, const float* __restrict__ w_attn,
                       uint16_t* __restrict__ wTval, uint16_t* __restrict__ wTout,
                       uint16_t* __restrict__ wTcat) {
    int k = blockIdx.x;          // 0..255
    int n = threadIdx.x;         // 0..255
    wTval[n * 256 + k] = f2bf(w_val[k * 256 + n]);
    wTout[n * 256 + k] = f2bf(w_out[k * 256 + n]);
    if (n < 64)       wTcat[n * 256 + k]        = f2bf(w_off[k * 64 + n]);
    else if (n < 96)  wTcat[n * 256 + k]        = f2bf(w_attn[k * 32 + (n - 64)]);
}

// ---------------------------------------------------------------------------
// Persistent GEMM  C[M x 256] = A[M x 256] * B[256 x 256] (+bias).
// grid 256 (1 block/CU), 512 threads (8 waves). B^T staged to LDS ONCE,
// preloaded to breg (wave w: cols 32w..+32, breg[2][8]); the 128-KB B region
// then becomes an A-ring (8x16KB f32 / 16x8KB bf16), tiles staged
// cooperatively by all 8 waves via global_load_lds. Counted per-wave vmcnt
// BEFORE the barrier (tiles are cross-wave staged), then s_barrier, then an
// empty memory-clobber so LDS reads stay below the barrier — but the
// compiler keeps full freedom to interleave stage/reads/MFMA in the region.
// PLANE: C = v[b][h][pix][32] bf16 via 32-KB LDS-transposed epilogue.
// ---------------------------------------------------------------------------
template<bool A_F32, bool OUT_F32, bool PLANE, int STRIPES>
__global__ __launch_bounds__(512, 2)
void gemm_pk(const void* __restrict__ Ap, const uint16_t* __restrict__ BT,
             void* __restrict__ Cp, const float* __restrict__ bias) {
    constexpr int TILEB = A_F32 ? 16384 : 8192;   // 16 rows x 256 k
    constexpr int NR    = 131072 / TILEB;         // ring slots: 8 or 16
    constexpr int T     = STRIPES * 4;            // tiles per block
    constexpr int LPT   = A_F32 ? 2 : 1;          // gloads/thread/tile
    __shared__ char SMEM[131072 + (PLANE ? 32768 : 0)];
    char* ring = SMEM;
    const int tid = threadIdx.x, w = tid >> 6, l = tid & 63;
    const int stripe0 = blockIdx.x * STRIPES;

    auto stageA = [&](int slot, int t) {
        const int gr0 = (stripe0 + (t >> 2)) * 64 + (t & 3) * 16;
        if constexpr (A_F32) {
#pragma unroll
            for (int c = 0; c < 2; ++c) {
                int loff = c * 8192 + tid * 16;
                int row = loff >> 10, x = loff & 1023;
                const char* src = (const char*)Ap + (size_t)(gr0 + row) * 1024
                                  + (x ^ ((row & 7) << 4));
                gload_lds16(src, ring + slot * 16384 + c * 8192 + w * 1024);
            }
        } else {
            int loff = tid * 16;
            int row = loff >> 9, x = loff & 511;
            const char* src = (const char*)Ap + (size_t)(gr0 + row) * 512
                              + (x ^ ((row & 7) << 4));
            gload_lds16(src, ring + slot * 8192 + w * 1024);
        }
    };

    // ---- prologue: B -> LDS -> breg, then fill A pipeline ----
#pragma unroll
    for (int c = 0; c < 16; ++c) {
        int loff = c * 8192 + tid * 16;
        int row = loff >> 9, x = loff & 511;
        const char* src = (const char*)BT + (size_t)row * 512 + (x ^ ((row & 7) << 4));
        gload_lds16(src, SMEM + c * 8192 + w * 1024);
    }
    WAITV(0);
    BAR();
    CLOBBER();
    short8v breg[2][8];
#pragma unroll
    for (int n = 0; n < 2; ++n) {
        int col = w * 32 + n * 16 + (l & 15);
        const char* base = SMEM + col * 512;
        const int sz = (col & 7) << 4;
#pragma unroll
        for (int k = 0; k < 8; ++k)
            breg[n][k] = *(const short8v*)(base + ((k * 64 + (l >> 4) * 16) ^ sz));
    }
    WAITLGKM();          // breg safely in regs before ring reuse
    BAR();
    CLOBBER();
#pragma unroll
    for (int t = 0; t < 6; ++t) stageA(t & (NR - 1), t);

    // ---- main pipeline ----
    for (int st = 0; st < STRIPES; ++st) {
        f32x4 acc[4][2] = {};
#pragma unroll
        for (int s = 0; s < 4; ++s) {
            const int t = st * 4 + s;
            const int rem = T - 1 - t;
            waitv_n((rem < 5 ? rem : 5) * LPT);   // own share of tile t landed
            BAR();                                 // all waves' shares landed
            CLOBBER();                             // reads stay below barrier
            if (t + 6 < T) stageA((t + 6) & (NR - 1), t + 6);
            const int slot = t & (NR - 1);
            short8v a[8];
            const int sz = (l & 7) << 4;
            if constexpr (A_F32) {
                const char* base = ring + slot * 16384 + (l & 15) * 1024;
#pragma unroll
                for (int k = 0; k < 8; ++k) {
                    int off = k * 128 + (l >> 4) * 32;
                    f32x4 lo = *(const f32x4*)(base + (off ^ sz));
                    f32x4 hi = *(const f32x4*)(base + ((off + 16) ^ sz));
                    union { uint32_t u[4]; short8v s8; } pk;
                    pk.u[0] = cvtpk(lo[0], lo[1]); pk.u[1] = cvtpk(lo[2], lo[3]);
                    pk.u[2] = cvtpk(hi[0], hi[1]); pk.u[3] = cvtpk(hi[2], hi[3]);
                    a[k] = pk.s8;
                }
            } else {
                const char* base = ring + slot * 8192 + (l & 15) * 512;
#pragma unroll
                for (int k = 0; k < 8; ++k)
                    a[k] = *(const short8v*)(base + ((k * 64 + (l >> 4) * 16) ^ sz));
            }
#pragma unroll
            for (int k = 0; k < 8; ++k)
#pragma unroll
                for (int n = 0; n < 2; ++n)
                    acc[s][n] = __builtin_amdgcn_mfma_f32_16x16x32_bf16(a[k], breg[n][k], acc[s][n], 0, 0, 0);
        }

        // ---- stripe epilogue ----
        const int gr0 = (stripe0 + st) * 64;
        if constexpr (PLANE) {
            char* Cs = SMEM + 131072;       // 32 KB C tile [64][256] u16, swizzled
#pragma unroll
            for (int s = 0; s < 4; ++s)
#pragma unroll
                for (int n = 0; n < 2; ++n) {
                    int lcol = w * 32 + n * 16 + (l & 15);
                    float bv = bias[lcol];
#pragma unroll
                    for (int r = 0; r < 4; ++r) {
                        int lrow = s * 16 + (l >> 4) * 4 + r;
                        *(uint16_t*)(Cs + ((lrow * 512 + lcol * 2) ^ ((lrow & 7) << 4)))
                            = f2bf(acc[s][n][r] + bv);
                    }
                }
            WAITLGKM();                     // own ds_writes drained
            BAR();                          // all waves' Cs writes visible
            CLOBBER();
            const int b_ = gr0 >> 14, pix0 = gr0 & 16383;
            char* pb = (char*)Cp + (((size_t)(b_ * 8 + w)) << 20) + (size_t)pix0 * 64;
#pragma unroll
            for (int i = 0; i < 4; ++i) {
                int fb = i * 1024 + l * 16;
                int lrow = fb >> 6, x = w * 64 + (fb & 63);
                uint4 d = *(const uint4*)(Cs + ((lrow * 512 + x) ^ ((lrow & 7) << 4)));
                *(uint4*)(pb + (size_t)lrow * 64 + (fb & 63)) = d;
            }
            // no trailing barrier: next epilogue is >=4 tile-barriers away
        } else {
#pragma unroll
            for (int s = 0; s < 4; ++s)
#pragma unroll
                for (int n = 0; n < 2; ++n) {
                    int col = w * 32 + n * 16 + (l & 15);
                    float bv = bias[col];
#pragma unroll
                    for (int r = 0; r < 4; ++r) {
                        int gr = gr0 + s * 16 + (l >> 4) * 4 + r;
                        float val = acc[s][n][r] + bv;
                        if constexpr (OUT_F32)
                            ((float*)Cp)[(size_t)gr * 256 + col] = val;
                        else
                            ((uint16_t*)Cp)[(size_t)gr * 256 + col] = f2bf(val);
                    }
                }
        }
    }
}

// ---------------------------------------------------------------------------
// proj: per 64 query rows, GEMM query[64x256] @ wTcat^T -> scores[64x96],
// then per (row, head): softmax + sampling locations, written HEAD-MAJOR:
//   itemH = ((b*8+h)*8192 + q);  locs[itemH][8], attnw[itemH][4]
// ---------------------------------------------------------------------------
__global__ __launch_bounds__(256, 2)
void proj_kernel(const float* __restrict__ Q, const uint16_t* __restrict__ WTcat,
                 const float* __restrict__ b_off, const float* __restrict__ b_attn,
                 const float* __restrict__ refp,
                 float* __restrict__ locs, float* __restrict__ attnw) {
    __shared__ uint16_t Bs[96 * 256];   // 48KB, [col][k], swizzled (512B rows)
    __shared__ uint16_t As[64 * 256];   // 32KB, [row][k], swizzled; reused as scores
    const int tid = threadIdx.x, w = tid >> 6, l = tid & 63;
    const int blk = blockIdx.x;

#pragma unroll
    for (int c = 0; c < 12; ++c) {
        int loff = (w * 12 + c) * 1024;
        int lofl = loff + l * 16;
        int row = lofl >> 9, colb = lofl & 511;
        const char* src = (const char*)WTcat + (size_t)row * 512 + (colb ^ ((row & 7) << 4));
        gload_lds16(src, (char*)Bs + loff);
    }
#pragma unroll
    for (int c = 0; c < 8; ++c) {
        int loff = tid * 16 + c * 4096;
        int row = loff >> 9, colb = loff & 511;
        const float* src = Q + (size_t)(blk * 64 + row) * 256 + (colb >> 1);
        float4 f0 = *(const float4*)src;
        float4 f1 = *(const float4*)(src + 4);
        uint4 pk;
        pk.x = (uint32_t)f2bf(f0.x) | ((uint32_t)f2bf(f0.y) << 16);
        pk.y = (uint32_t)f2bf(f0.z) | ((uint32_t)f2bf(f0.w) << 16);
        pk.z = (uint32_t)f2bf(f1.x) | ((uint32_t)f2bf(f1.y) << 16);
        pk.w = (uint32_t)f2bf(f1.z) | ((uint32_t)f2bf(f1.w) << 16);
        *(uint4*)((char*)As + row * 512 + (colb ^ ((row & 7) << 4))) = pk;
    }
    __syncthreads();

    f32x4 acc[6] = {};
    const int arow = w * 16 + (l & 15);
#pragma unroll
    for (int ks = 0; ks < 8; ++ks) {
        const int kb = ks * 64 + (l >> 4) * 16;
        short8v a = *(const short8v*)((const char*)As + arow * 512 + (kb ^ ((arow & 7) << 4)));
#pragma unroll
        for (int n = 0; n < 6; ++n) {
            int col = n * 16 + (l & 15);
            short8v b = *(const short8v*)((const char*)Bs + col * 512 + (kb ^ ((col & 7) << 4)));
            acc[n] = __builtin_amdgcn_mfma_f32_16x16x32_bf16(a, b, acc[n], 0, 0, 0);
        }
    }
    __syncthreads();
    float* scores = (float*)As;   // [64][96]
#pragma unroll
    for (int n = 0; n < 6; ++n)
#pragma unroll
        for (int r = 0; r < 4; ++r)
            scores[(w * 16 + (l >> 4) * 4 + r) * 96 + n * 16 + (l & 15)] = acc[n][r];
    __syncthreads();

    for (int it = tid; it < 512; it += 256) {
        int row = it >> 3, h = it & 7;
        int gq = blk * 64 + row;                       // b*NQ + q
        int b = gq >> 13, q = gq & 8191;
        size_t itemH = ((size_t)(b * 8 + h) << 13) | q;
        float s0 = scores[row * 96 + 64 + h * 4 + 0] + b_attn[h * 4 + 0];
        float s1 = scores[row * 96 + 64 + h * 4 + 1] + b_attn[h * 4 + 1];
        float s2 = scores[row * 96 + 64 + h * 4 + 2] + b_attn[h * 4 + 2];
        float s3 = scores[row * 96 + 64 + h * 4 + 3] + b_attn[h * 4 + 3];
        float mx = fmaxf(fmaxf(s0, s1), fmaxf(s2, s3));
        float e0 = __expf(s0 - mx), e1 = __expf(s1 - mx);
        float e2 = __expf(s2 - mx), e3 = __expf(s3 - mx);
        float inv = 1.0f / (e0 + e1 + e2 + e3);
        float rx = refp[gq * 2 + 0] * 128.0f - 0.5f;
        float ry = refp[gq * 2 + 1] * 128.0f - 0.5f;
        float ew[4] = { e0, e1, e2, e3 };
#pragma unroll
        for (int p = 0; p < 4; ++p) {
            float ox = scores[row * 96 + h * 8 + p * 2 + 0] + b_off[h * 8 + p * 2 + 0];
            float oy = scores[row * 96 + h * 8 + p * 2 + 1] + b_off[h * 8 + p * 2 + 1];
            locs[itemH * 8 + p * 2 + 0] = rx + ox;
            locs[itemH * 8 + p * 2 + 1] = ry + oy;
            attnw[itemH * 4 + p] = ew[p] * inv;
        }
    }
}

// ---------------------------------------------------------------------------
// sample: plane-major v[b][h][16384][32] bf16 (1MB per (b,h) plane).
// XCD-pinned: blockIdx&7 = h; 4 lanes/item, dwordx4 gathers.
// ---------------------------------------------------------------------------
__global__ __launch_bounds__(256)
void sample_kernel(const uint16_t* __restrict__ v, const float* __restrict__ locs,
                   const float* __restrict__ attnw, uint16_t* __restrict__ oatt) {
    const int bid = blockIdx.x;          // 8192 blocks
    const int h = bid & 7;
    const int rest = bid >> 3;           // 0..1023
    const int b = rest >> 7;             // 0..7
    const int chunk = rest & 127;        // 0..127
    const int qloc = threadIdx.x >> 2;   // 0..63
    const int dg = threadIdx.x & 3;      // dims dg*8..dg*8+7
    const int q = chunk * 64 + qloc;
    const size_t itemH = ((size_t)(b * 8 + h) << 13) | q;
    const char* plane = (const char*)v + ((size_t)(b * 8 + h) << 20);   // 1MB planes

    float4 l01 = ((const float4*)locs)[itemH * 2 + 0];
    float4 l23 = ((const float4*)locs)[itemH * 2 + 1];
    float4 aw4 = ((const float4*)attnw)[itemH];
    float pxs[4] = { l01.x, l01.z, l23.x, l23.z };
    float pys[4] = { l01.y, l01.w, l23.y, l23.w };
    float aws[4] = { aw4.x, aw4.y, aw4.z, aw4.w };

    float acc[8] = {};
#pragma unroll
    for (int p = 0; p < 4; ++p) {
        float px = pxs[p], py = pys[p], aw = aws[p];
        float fx = floorf(px), fy = floorf(py);
        float wx = px - fx, wy = py - fy;
        int x0 = (int)fx, y0 = (int)fy;
#pragma unroll
        for (int cy = 0; cy < 2; ++cy) {
            int yy = y0 + cy;
            float wyv = cy ? wy : 1.f - wy;
            bool yok = (unsigned)yy < (unsigned)IMG;
            int yc = min(max(yy, 0), IMG - 1);
#pragma unroll
            for (int cx = 0; cx < 2; ++cx) {
                int xx = x0 + cx;
                bool ok = yok && ((unsigned)xx < (unsigned)IMG);
                int xc = min(max(xx, 0), IMG - 1);
                float wgt = ok ? aw * (cx ? wx : 1.f - wx) * wyv : 0.f;
                const uint4 u = *(const uint4*)(plane + ((size_t)(yc * IMG + xc) << 6) + dg * 16);
                acc[0] += wgt * bf2f(u.x & 0xffffu);
                acc[1] += wgt * bf2f(u.x >> 16);
                acc[2] += wgt * bf2f(u.y & 0xffffu);
                acc[3] += wgt * bf2f(u.y >> 16);
                acc[4] += wgt * bf2f(u.z & 0xffffu);
                acc[5] += wgt * bf2f(u.z >> 16);
                acc[6] += wgt * bf2f(u.w & 0xffffu);
                acc[7] += wgt * bf2f(u.w >> 16);
            }
        }
    }
    const size_t bq = (size_t)b * NQ + q;
    uint4 out;
    out.x = (uint32_t)f2bf(acc[0]) | ((uint32_t)f2bf(acc[1]) << 16);
    out.y = (uint32_t)f2bf(acc[2]) | ((uint32_t)f2bf(acc[3]) << 16);
    out.z = (uint32_t)f2bf(acc[4]) | ((uint32_t)f2bf(acc[5]) << 16);
    out.w = (uint32_t)f2bf(acc[6]) | ((uint32_t)f2bf(acc[7]) << 16);
    *(uint4*)((char*)oatt + (bq * 256 + h * 32 + dg * 8) * 2) = out;
}

// ---------------------------------------------------------------------------
extern "C" void kernel_launch(void* const* d_in, const int* in_sizes, int n_in,
                              void* d_out, int out_size, void* d_ws, size_t ws_size,
                              hipStream_t stream) {
    const float* query  = (const float*)d_in[0];
    const float* refp   = (const float*)d_in[1];
    const float* value  = (const float*)d_in[2];
    const float* w_off  = (const float*)d_in[3];
    const float* b_off  = (const float*)d_in[4];
    const float* w_attn = (const float*)d_in[5];
    const float* b_attn = (const float*)d_in[6];
    const float* w_val  = (const float*)d_in[7];
    const float* b_val  = (const float*)d_in[8];
    const float* w_out  = (const float*)d_in[9];
    const float* b_out  = (const float*)d_in[10];

    char* ws = (char*)d_ws;
    uint16_t* v     = (uint16_t*)(ws);                    //  64 MB  [b][h][pix][32]
    uint16_t* oatt  = (uint16_t*)(ws + (64u << 20));      //  32 MB  [bq][256]
    float*    locs  = (float*)(ws + (96u << 20));         //  16 MB  head-major
    float*    attnw = (float*)(ws + (112u << 20));        //   8 MB  head-major
    uint16_t* wTval = (uint16_t*)(ws + (120u << 20));     // 128 KB
    uint16_t* wTout = (uint16_t*)(ws + (120u << 20) + 131072);
    uint16_t* wTcat = (uint16_t*)(ws + (120u << 20) + 262144);

    pack_w<<<256, 256, 0, stream>>>(w_val, w_out, w_off, w_attn, wTval, wTout, wTcat);
    // value projection: [131072 x 256] f32 @ wTval -> v (plane-major bf16)
    gemm_pk<true, false, true, 8><<<256, 512, 0, stream>>>(value, wTval, v, b_val);
    // query projections + softmax + locations (head-major records)
    proj_kernel<<<1024, 256, 0, stream>>>(query, wTcat, b_off, b_attn, refp, locs, attnw);
    // bilinear sampling -> out_attn bf16
    sample_kernel<<<8192, 256, 0, stream>>>(v, locs, attnw, oatt);
    // output projection: [65536 x 256] bf16 @ wTout + b_out -> f32 d_out
    gemm_pk<false, true, false, 4><<<256, 512, 0, stream>>>(oatt, wTout, (float*)d_out, b_out);
}